// Round 11
// baseline (417.116 us; speedup 1.0000x reference)
//
#include <hip/hip_runtime.h>
#include <hip/hip_fp16.h>
#include <cstddef>

// ---------------------------------------------------------------------------
// GCN-VAE on MI355X.
//   CSR build chain (hist -> bscan -> scatter -> final), with gemm1's 782
//   64-row tiles SPREAD across all four launches as filler blocks (blockIdx
//   split, no grid.sync) -> spmm1 (src-scaled gather, fp16) -> spmm2
//   (prescaled, fp32) -> mlz -> spmm_zg -> recon GEMM.
// R5: fp16 dinv-prescaled staging halves gather bytes; gender conv commuted
//     to (Âz)@Wg order so the one-hot argmax path stays fp32-exact.
// R6: 256B-align ws; mlz fusion; fp8 z staging + fused gagg. fp8 for Xs/hb
//     REJECTED: dz~0.015 -> ~100 gender argmax flips (absmax 1.0 cliff).
// R7: readlane gather: 52.4->54 -> NOT VALU-bound.
// R8: wider loads: 54->58 -> NOT VMEM-instr-bound. spmm_zg 4-row fp8 dword
//     gather WON -> kept.
// R9: U=16 A/B: 63 vs 52.4 -> deeper unroll HURTS. U=8 is the floor.
// R10: hist+gemm packed, scan->bscan: 419->411.
// R11: cooperative 3-phase build REJECTED: grid.sync spin = 280us/dispatch.
// R12: gemm1 tiles spread across all four CSR launches: 411->397.7. BEST.
// R13: parallel counting sort REGRESSED (double-pass scatter) -> reverted.
// R14/R15: recon matvec fused into spmm_zg REGRESSED 397.7->448 (per-wave
//     matvec re-reads 32KB Wdx per node, zero weight reuse) -> reverted.
// R16: R12 reproduced at 397.4. spmm pair at dual traffic(48us)/edge-
//     processing(~45us) floor -- zg's L2-resident 42us proves the
//     processing floor; feature-split passes can't win.
// R17: build-region probe: gemm tile RPT 4->8 (64-row tiles, 782 total,
//     32 FMA per LDS w-load instead of 16 -> LDS-read pressure halved;
//     bit-exact per-output FMA order). If build launches are gemm-slice
//     bound -> ~-10us; if unchanged -> region is CSR-bound, declare floor.
// ---------------------------------------------------------------------------

constexpr int R = 200;        // nodes per bucket (n=50000 -> exactly 250 buckets)
constexpr int NBUCK = 250;    // dst buckets
constexpr int NBLK = 250;     // edge-chunk blocks for hist/scatter
constexpr int SLABCAP = 12288;  // csr slab LDS capacity (mean bucket = 6400)

// One 64-row tile of Xs = fp16(x @ W1), unscaled (dinv folded into spmm1).
// sW is a 32KB LDS scratch owned by the calling block's branch.
// RPT=8: per LDS w-load 32 FMAs (vs 16 at RPT=4); per-(row,col) FMA order
// identical to the RPT=4 version -> bit-exact output.
__device__ __forceinline__ void gemm_tile64(
    int tile, const float* __restrict__ A, const float* __restrict__ W,
    __half* __restrict__ Ch, int n, float* sW) {
  constexpr int K = 128, M = 128, KT = 64, RPT = 8, CG = 32;
  const int tid = threadIdx.x;
  const int cgi = tid % CG;
  const int rs = tid / CG;
  const int row0 = tile * 64 + rs * RPT;

  const float* Arow[RPT];
#pragma unroll
  for (int rr = 0; rr < RPT; ++rr) {
    int row = row0 + rr;
    if (row > n - 1) row = n - 1;
    Arow[rr] = A + (size_t)row * K;
  }
  float4 acc[RPT];
#pragma unroll
  for (int rr = 0; rr < RPT; ++rr) acc[rr] = float4{0.f, 0.f, 0.f, 0.f};

  for (int kt = 0; kt < K; kt += KT) {
    if (kt) __syncthreads();
    for (int i = tid * 4; i < KT * M; i += 1024)
      *reinterpret_cast<float4*>(&sW[i]) =
          *reinterpret_cast<const float4*>(&W[kt * M + i]);
    __syncthreads();
#pragma unroll 2
    for (int k4 = 0; k4 < KT; k4 += 4) {
      float4 a[RPT];
#pragma unroll
      for (int rr = 0; rr < RPT; ++rr)
        a[rr] = *reinterpret_cast<const float4*>(Arow[rr] + kt + k4);
#pragma unroll
      for (int j = 0; j < 4; ++j) {
        float4 w2 = *reinterpret_cast<const float4*>(&sW[(k4 + j) * M + cgi * 4]);
#pragma unroll
        for (int rr = 0; rr < RPT; ++rr) {
          float av = reinterpret_cast<const float*>(&a[rr])[j];
          acc[rr].x += av * w2.x; acc[rr].y += av * w2.y;
          acc[rr].z += av * w2.z; acc[rr].w += av * w2.w;
        }
      }
    }
  }
#pragma unroll
  for (int rr = 0; rr < RPT; ++rr) {
    int row = row0 + rr;
    if (row < n) {
      __half2* d2 = reinterpret_cast<__half2*>(Ch + (size_t)row * M + cgi * 4);
      d2[0] = __floats2half2_rn(acc[rr].x, acc[rr].y);
      d2[1] = __floats2half2_rn(acc[rr].z, acc[rr].w);
    }
  }
}

// ---- Stage 1: histogram | gemm tiles [tbase, ...) ----
union HistSmem { int h[NBUCK]; float sW[64 * 128]; };
__global__ __launch_bounds__(256, 4) void hist_gemm_kernel(
    const int* __restrict__ dst, int* __restrict__ gh, int e, int chunk,
    const float* __restrict__ A, const float* __restrict__ W,
    __half* __restrict__ Ch, int n, int tbase) {
  __shared__ HistSmem sm;
  if (blockIdx.x < (unsigned)NBLK) {
    for (int t = threadIdx.x; t < NBUCK; t += 256) sm.h[t] = 0;
    __syncthreads();
    int beg = blockIdx.x * chunk;
    int fin = min(e, beg + chunk);
    for (int i = beg + threadIdx.x; i < fin; i += 256)
      atomicAdd(&sm.h[dst[i] / R], 1);
    __syncthreads();
    for (int t = threadIdx.x; t < NBUCK; t += 256)
      gh[t * NBLK + blockIdx.x] = sm.h[t];
  } else {
    gemm_tile64(tbase + (blockIdx.x - NBLK), A, W, Ch, n, sm.sW);
  }
}

// ---- Stage 2: bscan (offsets gh->ghs) | gemm tiles ----
union BscanSmem { struct { int s[256]; int sBase[NBUCK + 1]; } b; float sW[64 * 128]; };
__global__ __launch_bounds__(256, 4) void bscan_gemm_kernel(
    const int* __restrict__ gh, int* __restrict__ ghs,
    int* __restrict__ rowptr_n,
    const float* __restrict__ A, const float* __restrict__ W,
    __half* __restrict__ Ch, int n, int tbase) {
  __shared__ BscanSmem sm;
  const int tid = threadIdx.x;
  if (blockIdx.x < (unsigned)NBUCK) {
    const int b = blockIdx.x;
    // per-bucket totals (thread t sums bucket-row t; L2-resident)
    int tot = 0;
    if (tid < NBUCK) {
      const int* row = gh + tid * NBLK;
      for (int k = 0; k < NBLK; ++k) tot += row[k];
    }
    sm.b.s[tid] = tot;
    __syncthreads();
    for (int off = 1; off < 256; off <<= 1) {
      int t = (tid >= off) ? sm.b.s[tid - off] : 0;
      __syncthreads();
      sm.b.s[tid] += t;
      __syncthreads();
    }
    if (tid < NBUCK) sm.b.sBase[tid] = sm.b.s[tid] - tot;  // exclusive base
    if (tid == NBUCK - 1) sm.b.sBase[NBUCK] = sm.b.s[tid]; // total == e
    __syncthreads();

    // own-bucket local scan -> global offsets
    int v = (tid < NBLK) ? gh[b * NBLK + tid] : 0;
    sm.b.s[tid] = v;
    __syncthreads();
    for (int off = 1; off < 256; off <<= 1) {
      int t = (tid >= off) ? sm.b.s[tid - off] : 0;
      __syncthreads();
      sm.b.s[tid] += t;
      __syncthreads();
    }
    if (tid < NBLK) ghs[b * NBLK + tid] = sm.b.s[tid] - v + sm.b.sBase[b];
    if (b == 0 && tid == 0) *rowptr_n = sm.b.sBase[NBUCK];
  } else {
    gemm_tile64(tbase + (blockIdx.x - NBUCK), A, W, Ch, n, sm.sW);
  }
}

// ---- Stage 3: scatter | gemm tiles ----
union ScatSmem { int cur[NBUCK]; float sW[64 * 128]; };
__global__ __launch_bounds__(256, 4) void scatter_gemm_kernel(
    const int* __restrict__ src, const int* __restrict__ dst,
    const int* __restrict__ ghs, int* __restrict__ binned, int e, int chunk,
    const float* __restrict__ A, const float* __restrict__ W,
    __half* __restrict__ Ch, int n, int tbase) {
  __shared__ ScatSmem sm;
  if (blockIdx.x < (unsigned)NBLK) {
    for (int t = threadIdx.x; t < NBUCK; t += 256)
      sm.cur[t] = ghs[t * NBLK + blockIdx.x];
    __syncthreads();
    int beg = blockIdx.x * chunk;
    int fin = min(e, beg + chunk);
    for (int i = beg + threadIdx.x; i < fin; i += 256) {
      int d = dst[i];
      int b = d / R;
      int p = atomicAdd(&sm.cur[b], 1);
      binned[p] = ((d - b * R) << 16) | src[i];
    }
  } else {
    gemm_tile64(tbase + (blockIdx.x - NBLK), A, W, Ch, n, sm.sW);
  }
}

// ---- Stage 4: final (deg/rowptr/dinv/csr) | gemm tiles ----
union FinSmem {
  struct { int sdeg[R]; int sscan[256]; int scur[R]; int slab[SLABCAP]; } f;
  float sW[64 * 128];
};
__global__ __launch_bounds__(256, 3) void final_gemm_kernel(
    const int* __restrict__ binned, const int* __restrict__ ghs,
    int* __restrict__ rowptr, int* __restrict__ csr,
    float* __restrict__ dinv, int n, int e,
    const float* __restrict__ A, const float* __restrict__ W,
    __half* __restrict__ Ch, int tbase, int T) {
  __shared__ FinSmem sm;
  const int tid = threadIdx.x;
  if (blockIdx.x < (unsigned)NBUCK) {
    const int b = blockIdx.x;
    const int base = ghs[b * NBLK];
    const int endv = (b < NBUCK - 1) ? ghs[(b + 1) * NBLK] : e;
    const int cnt = endv - base;

    if (tid < R) sm.f.sdeg[tid] = 0;
    __syncthreads();
    for (int k = base + tid; k < endv; k += 256)
      atomicAdd(&sm.f.sdeg[binned[k] >> 16], 1);
    __syncthreads();

    int dv = (tid < R) ? sm.f.sdeg[tid] : 0;
    sm.f.sscan[tid] = dv;
    __syncthreads();
    for (int off = 1; off < 256; off <<= 1) {
      int t = (tid >= off) ? sm.f.sscan[tid - off] : 0;
      __syncthreads();
      sm.f.sscan[tid] += t;
      __syncthreads();
    }
    int excl = sm.f.sscan[tid] - dv;
    int node = b * R + tid;
    if (tid < R && node < n) {
      rowptr[node] = base + excl;
      dinv[node] = 1.0f / sqrtf((float)dv + 1.0f);  // +1 self-loop
      sm.f.scur[tid] = excl;
    }
    __syncthreads();

    const bool fits = (cnt <= SLABCAP);
    for (int k = base + tid; k < endv; k += 256) {
      int rec = binned[k];
      int p = atomicAdd(&sm.f.scur[rec >> 16], 1);
      int s = rec & 0xFFFF;
      if (fits) sm.f.slab[p] = s;
      else csr[base + p] = s;
    }
    __syncthreads();
    if (fits)
      for (int k = tid; k < cnt; k += 256) csr[base + k] = sm.f.slab[k];
  } else {
    int t0 = tbase + (blockIdx.x - NBUCK);
    if (t0 < T) gemm_tile64(t0, A, W, Ch, n, sm.sW);
  }
}

// ---------------------------------------------------------------------------
// GEMM: C[n,M] = A[n,K] @ W[K,M] (+bias). Used for the recon head only.
// ---------------------------------------------------------------------------
template <int K, int M, int KT, int RPT, bool BIAS>
__global__ __launch_bounds__(256, 4) void gemm_kernel(
    const float* __restrict__ A, const float* __restrict__ W,
    const float* __restrict__ bias, float* __restrict__ C, int n) {
  constexpr int CG = M / 4;
  constexpr int RS = 256 / CG;
  constexpr int RPB = RS * RPT;
  __shared__ float sW[KT * M];
  const int cg = threadIdx.x % CG;
  const int rs = threadIdx.x / CG;
  const int row0 = blockIdx.x * RPB + rs * RPT;

  const float* Arow[RPT];
#pragma unroll
  for (int rr = 0; rr < RPT; ++rr) {
    int row = row0 + rr;
    if (row > n - 1) row = n - 1;
    Arow[rr] = A + (size_t)row * K;
  }

  float4 acc[RPT];
#pragma unroll
  for (int rr = 0; rr < RPT; ++rr) acc[rr] = float4{0.f, 0.f, 0.f, 0.f};

  for (int kt = 0; kt < K; kt += KT) {
    if (kt) __syncthreads();
    for (int i = threadIdx.x * 4; i < KT * M; i += 1024)
      *reinterpret_cast<float4*>(&sW[i]) =
          *reinterpret_cast<const float4*>(&W[kt * M + i]);
    __syncthreads();
#pragma unroll 4
    for (int k4 = 0; k4 < KT; k4 += 4) {
      float4 a[RPT];
#pragma unroll
      for (int rr = 0; rr < RPT; ++rr)
        a[rr] = *reinterpret_cast<const float4*>(Arow[rr] + kt + k4);
#pragma unroll
      for (int j = 0; j < 4; ++j) {
        float4 w = *reinterpret_cast<const float4*>(&sW[(k4 + j) * M + cg * 4]);
#pragma unroll
        for (int rr = 0; rr < RPT; ++rr) {
          float av = reinterpret_cast<const float*>(&a[rr])[j];
          acc[rr].x += av * w.x;
          acc[rr].y += av * w.y;
          acc[rr].z += av * w.z;
          acc[rr].w += av * w.w;
        }
      }
    }
  }

  float4 bv = float4{0.f, 0.f, 0.f, 0.f};
  if (BIAS) bv = *reinterpret_cast<const float4*>(&bias[cg * 4]);
#pragma unroll
  for (int rr = 0; rr < RPT; ++rr) {
    int row = row0 + rr;
    if (row < n) {
      float4 o = acc[rr];
      if (BIAS) { o.x += bv.x; o.y += bv.y; o.z += bv.z; o.w += bv.w; }
      *reinterpret_cast<float4*>(&C[(size_t)row * M + cg * 4]) = o;
    }
  }
}

// ---------------------------------------------------------------------------
// SpMM (F=128), one wave per node, U=8 gather pipeline (R9-verified floor).
// SRCSCALE=true : Xs is UNSCALED fp16(xw); apply dinv[src] per edge via a
//                 wave-uniform broadcast load + FMA (spmm1).
// SRCSCALE=false: input already dinv-prescaled (hb) -- byte-exact R6 kernel
//                 (spmm2).
// ---------------------------------------------------------------------------
template <bool SRCSCALE, bool BIAS, bool RELU, bool HALF_OUT>
__global__ __launch_bounds__(256) void spmm128_kernel(
    const __half* __restrict__ Xs, void* __restrict__ Yout,
    const int* __restrict__ rowptr, const int* __restrict__ csr,
    const float* __restrict__ dinv, const float* __restrict__ bias, int n) {
  int wid = (blockIdx.x * blockDim.x + threadIdx.x) >> 6;
  int lane = threadIdx.x & 63;
  if (wid >= n) return;
  int beg = rowptr[wid];
  int end = rowptr[wid + 1];
  constexpr int U = 8;
  float a0[U], a1[U];
#pragma unroll
  for (int uu = 0; uu < U; ++uu) { a0[uu] = 0.f; a1[uu] = 0.f; }

  for (int base = beg; base < end; base += 64) {
    int m = end - base;
    if (m > 64) m = 64;
    int idx = (lane < m) ? csr[base + lane] : 0;
    int j = 0;
    for (; j + U <= m; j += U) {
      const __half2* rows[U];
      float ds[U];
#pragma unroll
      for (int uu = 0; uu < U; ++uu) {
        int i = __shfl(idx, j + uu, 64);
        rows[uu] = reinterpret_cast<const __half2*>(Xs + (size_t)i * 128);
        if (SRCSCALE) ds[uu] = dinv[i];  // wave-uniform broadcast load
      }
      __half2 v[U];
#pragma unroll
      for (int uu = 0; uu < U; ++uu) v[uu] = rows[uu][lane];
#pragma unroll
      for (int uu = 0; uu < U; ++uu) {
        float2 f = __half22float2(v[uu]);
        if (SRCSCALE) {
          a0[uu] += ds[uu] * f.x;
          a1[uu] += ds[uu] * f.y;
        } else {
          a0[uu] += f.x;
          a1[uu] += f.y;
        }
      }
    }
    for (; j < m; ++j) {
      int i = __shfl(idx, j, 64);
      const __half2* row = reinterpret_cast<const __half2*>(Xs + (size_t)i * 128);
      float2 f = __half22float2(row[lane]);
      if (SRCSCALE) {
        float ds = dinv[i];
        a0[0] += ds * f.x;
        a1[0] += ds * f.y;
      } else {
        a0[0] += f.x;
        a1[0] += f.y;
      }
    }
  }

  float t0 = 0.f, t1 = 0.f;
#pragma unroll
  for (int uu = 0; uu < U; ++uu) { t0 += a0[uu]; t1 += a1[uu]; }

  float di = dinv[wid];

  // self-loop: + dinv[wid]*Xs[wid] (SRCSCALE) or + Xs[wid] (prescaled)
  float2 sf = __half22float2(
      reinterpret_cast<const __half2*>(Xs + (size_t)wid * 128)[lane]);
  if (SRCSCALE) {
    t0 += di * sf.x;
    t1 += di * sf.y;
  } else {
    t0 += sf.x;
    t1 += sf.y;
  }

  float r0 = di * t0;
  float r1 = di * t1;
  if (BIAS) { r0 += bias[lane * 2]; r1 += bias[lane * 2 + 1]; }
  if (RELU) { r0 = fmaxf(r0, 0.f); r1 = fmaxf(r1, 0.f); }

  if (HALF_OUT) {
    reinterpret_cast<__half2*>((__half*)Yout + (size_t)wid * 128)[lane] =
        __floats2half2_rn(di * r0, di * r1);
  } else {
    float2 o = {r0, r1};
    reinterpret_cast<float2*>((float*)Yout + (size_t)wid * 128)[lane] = o;
  }
}

// ---------------------------------------------------------------------------
// mlz: fused mu/logvar GEMMs (hagg read ONCE) + z + fp8 z-staging + gender
// logits (commuted, fp32-exact) + label head.
// ---------------------------------------------------------------------------
__global__ __launch_bounds__(256, 4) void mlz_kernel(
    const float* __restrict__ hagg,
    const float* __restrict__ Wmu, const float* __restrict__ bmu,
    const float* __restrict__ Wls, const float* __restrict__ bls,
    const float* __restrict__ eps, const float* __restrict__ dinv,
    const float* __restrict__ Wg, const float* __restrict__ Wlc,
    const float* __restrict__ blc,
    float* __restrict__ out_mu, float* __restrict__ out_lv,
    float* __restrict__ out_z, unsigned int* __restrict__ zh8,
    float2* __restrict__ zgs, float* __restrict__ out_label, int n) {
  constexpr int K = 128, M = 64, KT = 64, RPT = 4;
  constexpr int CG = M / 4;       // 16
  constexpr int RS = 256 / CG;    // 16
  constexpr int RPB = RS * RPT;   // 64
  __shared__ float sWm[KT * M];
  __shared__ float sWl[KT * M];
  const int cg = threadIdx.x % CG;
  const int rs = threadIdx.x / CG;
  const int row0 = blockIdx.x * RPB + rs * RPT;

  const float* Arow[RPT];
#pragma unroll
  for (int rr = 0; rr < RPT; ++rr) {
    int row = row0 + rr;
    if (row > n - 1) row = n - 1;
    Arow[rr] = hagg + (size_t)row * K;
  }

  float4 am[RPT], al[RPT];
#pragma unroll
  for (int rr = 0; rr < RPT; ++rr) {
    am[rr] = float4{0.f, 0.f, 0.f, 0.f};
    al[rr] = float4{0.f, 0.f, 0.f, 0.f};
  }

  for (int kt = 0; kt < K; kt += KT) {
    if (kt) __syncthreads();
    for (int i = threadIdx.x * 4; i < KT * M; i += 1024) {
      *reinterpret_cast<float4*>(&sWm[i]) =
          *reinterpret_cast<const float4*>(&Wmu[kt * M + i]);
      *reinterpret_cast<float4*>(&sWl[i]) =
          *reinterpret_cast<const float4*>(&Wls[kt * M + i]);
    }
    __syncthreads();
#pragma unroll 2
    for (int k4 = 0; k4 < KT; k4 += 4) {
      float4 a[RPT];
#pragma unroll
      for (int rr = 0; rr < RPT; ++rr)
        a[rr] = *reinterpret_cast<const float4*>(Arow[rr] + kt + k4);
#pragma unroll
      for (int j = 0; j < 4; ++j) {
        float4 wm = *reinterpret_cast<const float4*>(&sWm[(k4 + j) * M + cg * 4]);
        float4 wl = *reinterpret_cast<const float4*>(&sWl[(k4 + j) * M + cg * 4]);
#pragma unroll
        for (int rr = 0; rr < RPT; ++rr) {
          float av = reinterpret_cast<const float*>(&a[rr])[j];
          am[rr].x += av * wm.x; am[rr].y += av * wm.y;
          am[rr].z += av * wm.z; am[rr].w += av * wm.w;
          al[rr].x += av * wl.x; al[rr].y += av * wl.y;
          al[rr].z += av * wl.z; al[rr].w += av * wl.w;
        }
      }
    }
  }

  float4 bm = *reinterpret_cast<const float4*>(&bmu[cg * 4]);
  float4 bl = *reinterpret_cast<const float4*>(&bls[cg * 4]);
  float wg0[4], wg1[4], wlcv[4];
#pragma unroll
  for (int cc = 0; cc < 4; ++cc) {
    int c = cg * 4 + cc;
    wg0[cc] = Wg[c * 2 + 0];
    wg1[cc] = Wg[c * 2 + 1];
    wlcv[cc] = Wlc[c];
  }
  float blc0 = blc[0];

#pragma unroll
  for (int rr = 0; rr < RPT; ++rr) {
    int row = row0 + rr;
    if (row < n) {  // uniform across the 16-lane cg-group
      float4 mu4 = {am[rr].x + bm.x, am[rr].y + bm.y,
                    am[rr].z + bm.z, am[rr].w + bm.w};
      float4 lv4 = {al[rr].x + bl.x, al[rr].y + bl.y,
                    al[rr].z + bl.z, al[rr].w + bl.w};
      float4 e4 = *reinterpret_cast<const float4*>(&eps[(size_t)row * 64 + cg * 4]);
      float4 z4 = {e4.x * expf(0.5f * lv4.x) + mu4.x,
                   e4.y * expf(0.5f * lv4.y) + mu4.y,
                   e4.z * expf(0.5f * lv4.z) + mu4.z,
                   e4.w * expf(0.5f * lv4.w) + mu4.w};
      *reinterpret_cast<float4*>(&out_mu[(size_t)row * 64 + cg * 4]) = mu4;
      *reinterpret_cast<float4*>(&out_lv[(size_t)row * 64 + cg * 4]) = lv4;
      *reinterpret_cast<float4*>(&out_z[(size_t)row * 64 + cg * 4]) = z4;
      float di = dinv[row];
      int pw = __builtin_amdgcn_cvt_pk_fp8_f32(di * z4.x, di * z4.y, 0, false);
      pw = __builtin_amdgcn_cvt_pk_fp8_f32(di * z4.z, di * z4.w, pw, true);
      zh8[(size_t)row * 16 + cg] = (unsigned int)pw;
      float pg0 = z4.x * wg0[0] + z4.y * wg0[1] + z4.z * wg0[2] + z4.w * wg0[3];
      float pg1 = z4.x * wg1[0] + z4.y * wg1[1] + z4.z * wg1[2] + z4.w * wg1[3];
      float pl  = z4.x * wlcv[0] + z4.y * wlcv[1] + z4.z * wlcv[2] + z4.w * wlcv[3];
#pragma unroll
      for (int off = 1; off < 16; off <<= 1) {
        pg0 += __shfl_xor(pg0, off, 64);
        pg1 += __shfl_xor(pg1, off, 64);
        pl  += __shfl_xor(pl, off, 64);
      }
      if (cg == 0) {
        zgs[row] = float2{di * pg0, di * pg1};
        out_label[row] = pl + blc0;
      }
    }
  }
}

// ---------------------------------------------------------------------------
// fp8 dword unpack-accumulate: byte b of d is feature 4c+b.
// ---------------------------------------------------------------------------
__device__ __forceinline__ void fp8x4acc(unsigned d, float* a) {
#if defined(__has_builtin) && __has_builtin(__builtin_amdgcn_cvt_pk_f32_fp8)
  typedef float f32x2 __attribute__((ext_vector_type(2)));
  f32x2 lo = __builtin_amdgcn_cvt_pk_f32_fp8((int)d, false);
  f32x2 hi = __builtin_amdgcn_cvt_pk_f32_fp8((int)d, true);
  a[0] += lo.x; a[1] += lo.y; a[2] += hi.x; a[3] += hi.y;
#else
  a[0] += __builtin_amdgcn_cvt_f32_fp8((int)d, 0);
  a[1] += __builtin_amdgcn_cvt_f32_fp8((int)d, 1);
  a[2] += __builtin_amdgcn_cvt_f32_fp8((int)d, 2);
  a[3] += __builtin_amdgcn_cvt_f32_fp8((int)d, 3);
#endif
}

// ---------------------------------------------------------------------------
// spmm_zg (R8-proven): 4 rows per wave-load fp8 dword gather + fused gender
// aggregation (verbatim fp32 path) + gumbel-softmax hard head.
// ---------------------------------------------------------------------------
__global__ __launch_bounds__(256) void spmm_zg_kernel(
    const unsigned char* __restrict__ zh8, const float2* __restrict__ zgs,
    float* __restrict__ zagg, const int* __restrict__ rowptr,
    const int* __restrict__ csr, const float* __restrict__ dinv,
    const float* __restrict__ bg, const float* __restrict__ u,
    float* __restrict__ out_gender, int n) {
  int wid = (blockIdx.x * blockDim.x + threadIdx.x) >> 6;
  int lane = threadIdx.x & 63;
  if (wid >= n) return;
  int beg = rowptr[wid];
  int end = rowptr[wid + 1];
  const int g = lane >> 4;   // row group 0..3
  const int c = lane & 15;   // feature quad: features 4c..4c+3
  const int coff = c * 4;

  float accA[4], accB[4];
#pragma unroll
  for (int f = 0; f < 4; ++f) { accA[f] = 0.f; accB[f] = 0.f; }
  float ga0 = 0.f, ga1 = 0.f;

  for (int base = beg; base < end; base += 64) {
    int m = end - base;
    if (m > 64) m = 64;
    int idx = 0;
    if (lane < m) {
      idx = csr[base + lane];
      float2 gz = zgs[idx];   // per-lane gender-logit accumulation (exact)
      ga0 += gz.x;
      ga1 += gz.y;
    }
    int j = 0;
    for (; j + 8 <= m; j += 8) {
      int i0 = __shfl(idx, j + g, 64);
      int i1 = __shfl(idx, j + 4 + g, 64);
      unsigned d0 = *reinterpret_cast<const unsigned*>(
          zh8 + (size_t)(unsigned)i0 * 64 + coff);
      unsigned d1 = *reinterpret_cast<const unsigned*>(
          zh8 + (size_t)(unsigned)i1 * 64 + coff);
      fp8x4acc(d0, accA);
      fp8x4acc(d1, accB);
    }
    if (j < m) {  // masked trailing step (up to 7 edges)
      int e0 = j + g;
      int e1 = j + 4 + g;
      int i0 = __shfl(idx, min(e0, m - 1), 64);
      int i1 = __shfl(idx, min(e1, m - 1), 64);
      unsigned d0 = *reinterpret_cast<const unsigned*>(
          zh8 + (size_t)(unsigned)i0 * 64 + coff);
      unsigned d1 = *reinterpret_cast<const unsigned*>(
          zh8 + (size_t)(unsigned)i1 * 64 + coff);
      if (e0 >= m) d0 = 0u;   // fp8 0x00 == +0.0
      if (e1 >= m) d1 = 0u;
      fp8x4acc(d0, accA);
      fp8x4acc(d1, accB);
    }
  }

  // combine the 8 partials (zagg order free: recon-only path)
  float t[4];
#pragma unroll
  for (int f = 0; f < 4; ++f) t[f] = accA[f] + accB[f];
#pragma unroll
  for (int f = 0; f < 4; ++f) t[f] += __shfl_xor(t[f], 16, 64);
#pragma unroll
  for (int f = 0; f < 4; ++f) t[f] += __shfl_xor(t[f], 32, 64);

  float di = dinv[wid];
  if (lane < 16) {
    unsigned ds = *reinterpret_cast<const unsigned*>(
        zh8 + (size_t)wid * 64 + coff);
    fp8x4acc(ds, t);  // self-loop
    float4 o = {di * t[0], di * t[1], di * t[2], di * t[3]};
    *reinterpret_cast<float4*>(&zagg[(size_t)wid * 64 + 4 * c]) = o;
  }

  for (int off = 32; off > 0; off >>= 1) {
    ga0 += __shfl_xor(ga0, off, 64);
    ga1 += __shfl_xor(ga1, off, 64);
  }
  if (lane == 0) {
    float2 self = zgs[wid];
    ga0 += self.x;
    ga1 += self.y;
    float lg0 = di * ga0 + bg[0];
    float lg1 = di * ga1 + bg[1];
    float u0 = u[(size_t)wid * 2 + 0];
    float u1 = u[(size_t)wid * 2 + 1];
    float g0 = -logf(-logf(u0 + 1e-20f) + 1e-20f);
    float g1 = -logf(-logf(u1 + 1e-20f) + 1e-20f);
    float a0 = lg0 + g0, a1 = lg1 + g1;
    float mx = fmaxf(a0, a1);
    float e0 = expf(a0 - mx), e1 = expf(a1 - mx);
    float s = e0 + e1;
    float y0 = e0 / s, y1 = e1 / s;
    float h0 = (y1 > y0) ? 0.f : 1.f;  // argmax, first index wins ties
    float h1 = 1.f - h0;
    out_gender[(size_t)wid * 2 + 0] = (h0 - y0) + y0;
    out_gender[(size_t)wid * 2 + 1] = (h1 - y1) + y1;
  }
}

extern "C" void kernel_launch(void* const* d_in, const int* in_sizes, int n_in,
                              void* d_out, int out_size, void* d_ws, size_t ws_size,
                              hipStream_t stream) {
  const float* x   = (const float*)d_in[0];
  const int*   ei  = (const int*)d_in[1];
  const float* eps = (const float*)d_in[2];
  const float* u   = (const float*)d_in[3];
  const float* W1  = (const float*)d_in[4];
  const float* b1  = (const float*)d_in[5];
  const float* Wmu = (const float*)d_in[6];
  const float* bmu = (const float*)d_in[7];
  const float* Wls = (const float*)d_in[8];
  const float* bls = (const float*)d_in[9];
  const float* Wdx = (const float*)d_in[10];
  const float* bdx = (const float*)d_in[11];
  const float* Wg  = (const float*)d_in[12];
  const float* bg  = (const float*)d_in[13];
  const float* Wlc = (const float*)d_in[14];
  const float* blc = (const float*)d_in[15];

  const int n = in_sizes[0] / 128;  // 50000
  const int e = in_sizes[1] / 2;    // 1600000
  const int* esrc = ei;
  const int* edst = ei + e;

  float* out = (float*)d_out;
  float* out_recon  = out;                            // n*128
  float* out_gender = out + (size_t)n * 128;          // n*2
  float* out_label  = out_gender + (size_t)n * 2;     // n
  float* out_mu     = out_label + n;                  // n*64
  float* out_lv     = out_mu + (size_t)n * 64;        // n*64
  float* out_z      = out_lv + (size_t)n * 64;        // n*64

  // Workspace layout, every buffer 256B-aligned.
  char* w = (char*)d_ws;
  size_t off = 0;
  auto alloc = [&](size_t bytes) {
    char* p = w + off;
    off = (off + bytes + 255) & ~(size_t)255;
    return p;
  };
  float* dinv  = (float*)alloc((size_t)n * 4);
  int* rowptr  = (int*)alloc((size_t)(n + 1) * 4);
  int* csr     = (int*)alloc((size_t)e * 4);
  int* gh      = (int*)alloc((size_t)NBUCK * NBLK * 4);
  int* ghs     = (int*)alloc((size_t)NBUCK * NBLK * 4);
  __half* Xs   = (__half*)alloc((size_t)n * 128 * 2);  // later: zh8 (n*64 B)
  __half* hb   = (__half*)alloc((size_t)n * 128 * 2);  // later: zagg (n*64 f32)
  float2* zgs  = (float2*)alloc((size_t)n * 8);
  unsigned char* zh8 = (unsigned char*)Xs;  // alias (Xs dead after spmm1)
  float* zagg  = (float*)hb;                // alias (hb dead after spmm2)
  float* hagg  = out_recon;                 // free until recon GEMM
  int* binned  = (int*)out_lv;              // free until mlz writes out_lv

  const int chunk = (e + NBLK - 1) / NBLK;  // 6400
  const int GBLK = (n + 31) / 32;           // 1563 recon-gemm blocks
  const int T = (n + 63) / 64;              // 782 gemm1 tiles (64-row)

  // gemm1 tile split across the four CSR launches
  const int TH = 250, TB = 230, TS = 170;
  const int TF = T - TH - TB - TS;          // 132

  // --- CSR build chain, gemm1 tiles spread as filler blocks ---
  hist_gemm_kernel<<<NBLK + TH, 256, 0, stream>>>(
      edst, gh, e, chunk, x, W1, Xs, n, 0);
  bscan_gemm_kernel<<<NBUCK + TB, 256, 0, stream>>>(
      gh, ghs, &rowptr[n], x, W1, Xs, n, TH);
  scatter_gemm_kernel<<<NBLK + TS, 256, 0, stream>>>(
      esrc, edst, ghs, binned, e, chunk, x, W1, Xs, n, TH + TB);
  final_gemm_kernel<<<NBUCK + TF, 256, 0, stream>>>(
      binned, ghs, rowptr, csr, dinv, n, e, x, W1, Xs, TH + TB + TS, T);

  // --- dense/sparse pipeline ---
  // hb = fp16(dinv * relu(A_hat*xw + b1)); Xs unscaled -> SRCSCALE gather
  spmm128_kernel<true, true, true, true>
      <<<(n + 3) / 4, 256, 0, stream>>>(Xs, hb, rowptr, csr, dinv, b1, n);
  // hagg = A_hat * h  (fp32, into out_recon region; hb prescaled -> R6-exact)
  spmm128_kernel<false, false, false, false>
      <<<(n + 3) / 4, 256, 0, stream>>>(hb, hagg, rowptr, csr, dinv, nullptr, n);
  // mu / lv / z / zh8 / zgs / label — fused (overwrites binned via out_lv: dead)
  mlz_kernel<<<(n + 63) / 64, 256, 0, stream>>>(
      hagg, Wmu, bmu, Wls, bls, eps, dinv, Wg, Wlc, blc,
      out_mu, out_lv, out_z, (unsigned int*)zh8, zgs, out_label, n);
  // zagg (fp8 gather) + gender aggregation + gumbel head
  spmm_zg_kernel<<<(n + 3) / 4, 256, 0, stream>>>(
      zh8, (const float2*)zgs, zagg, rowptr, csr, dinv, bg, u, out_gender, n);
  // recon = zagg @ W_dx + b_dx (overwrites hagg — dead)
  gemm_kernel<64, 128, 64, 4, true>
      <<<GBLK, 256, 0, stream>>>(zagg, Wdx, bdx, out_recon, n);
}

// Round 12
// 393.235 us; speedup vs baseline: 1.0607x; 1.0607x over previous
//
#include <hip/hip_runtime.h>
#include <hip/hip_fp16.h>
#include <cstddef>

// ---------------------------------------------------------------------------
// GCN-VAE on MI355X.
//   CSR build chain (hist -> bscan -> scatter -> final), with gemm1's 1563
//   row-tiles SPREAD across all four launches as filler blocks (blockIdx
//   split, no grid.sync) -> spmm1 (src-scaled gather, fp16) -> spmm2
//   (prescaled, fp32) -> mlz -> spmm_zg -> recon GEMM.
// R5: fp16 dinv-prescaled staging halves gather bytes; gender conv commuted
//     to (Âz)@Wg order so the one-hot argmax path stays fp32-exact.
// R6: 256B-align ws; mlz fusion; fp8 z staging + fused gagg. fp8 for Xs/hb
//     REJECTED: dz~0.015 -> ~100 gender argmax flips (absmax 1.0 cliff).
// R7: readlane gather: 52.4->54 -> NOT VALU-bound.
// R8: wider loads: 54->58 -> NOT VMEM-instr-bound. spmm_zg 4-row fp8 dword
//     gather WON -> kept.
// R9: U=16 A/B: 63 vs 52.4 -> deeper unroll HURTS. U=8 is the floor.
// R10: hist+gemm packed, scan->bscan: 419->411.
// R11: cooperative 3-phase build REJECTED: grid.sync spin = 280us/dispatch.
// R12: gemm1 tiles spread across all four CSR launches: 411->397.7. BEST.
// R13: parallel counting sort REGRESSED (double-pass scatter) -> reverted.
// R14/R15: recon matvec fused into spmm_zg REGRESSED 397.7->448 (per-wave
//     matvec re-reads 32KB Wdx per node, zero weight reuse) -> reverted.
// R16: R12 reproduced at 397.4. spmm pair at dual traffic(48us)/edge-
//     processing(~45us) floor.
// R17: gemm tile RPT 4->8 REGRESSED 397.4->417 (VGPR pressure in branchy
//     filler kernels + tile-count halving worsens launch tail) -> reverted.
//     R12 config now bounded worse from five directions (R11/R13/R14/R17).
// R18: R12/R16 exact restore (session best, reproduced twice). Structural
//     floor: 307MB mandatory gather traffic @ ~3.2TB/s beyond-L2 + ~190us
//     dependent build/GEMM/head work with no legal overlap remaining.
// ---------------------------------------------------------------------------

constexpr int R = 200;        // nodes per bucket (n=50000 -> exactly 250 buckets)
constexpr int NBUCK = 250;    // dst buckets
constexpr int NBLK = 250;     // edge-chunk blocks for hist/scatter
constexpr int SLABCAP = 12288;  // csr slab LDS capacity (mean bucket = 6400)

// One 32-row tile of Xs = fp16(x @ W1), unscaled (dinv folded into spmm1).
// sW is a 32KB LDS scratch owned by the calling block's branch.
__device__ __forceinline__ void gemm_tile32(
    int tile, const float* __restrict__ A, const float* __restrict__ W,
    __half* __restrict__ Ch, int n, float* sW) {
  constexpr int K = 128, M = 128, KT = 64, RPT = 4, CG = 32;
  const int tid = threadIdx.x;
  const int cgi = tid % CG;
  const int rs = tid / CG;
  const int row0 = tile * 32 + rs * RPT;

  const float* Arow[RPT];
#pragma unroll
  for (int rr = 0; rr < RPT; ++rr) {
    int row = row0 + rr;
    if (row > n - 1) row = n - 1;
    Arow[rr] = A + (size_t)row * K;
  }
  float4 acc[RPT];
#pragma unroll
  for (int rr = 0; rr < RPT; ++rr) acc[rr] = float4{0.f, 0.f, 0.f, 0.f};

  for (int kt = 0; kt < K; kt += KT) {
    if (kt) __syncthreads();
    for (int i = tid * 4; i < KT * M; i += 1024)
      *reinterpret_cast<float4*>(&sW[i]) =
          *reinterpret_cast<const float4*>(&W[kt * M + i]);
    __syncthreads();
#pragma unroll 4
    for (int k4 = 0; k4 < KT; k4 += 4) {
      float4 a[RPT];
#pragma unroll
      for (int rr = 0; rr < RPT; ++rr)
        a[rr] = *reinterpret_cast<const float4*>(Arow[rr] + kt + k4);
#pragma unroll
      for (int j = 0; j < 4; ++j) {
        float4 w2 = *reinterpret_cast<const float4*>(&sW[(k4 + j) * M + cgi * 4]);
#pragma unroll
        for (int rr = 0; rr < RPT; ++rr) {
          float av = reinterpret_cast<const float*>(&a[rr])[j];
          acc[rr].x += av * w2.x; acc[rr].y += av * w2.y;
          acc[rr].z += av * w2.z; acc[rr].w += av * w2.w;
        }
      }
    }
  }
#pragma unroll
  for (int rr = 0; rr < RPT; ++rr) {
    int row = row0 + rr;
    if (row < n) {
      __half2* d2 = reinterpret_cast<__half2*>(Ch + (size_t)row * M + cgi * 4);
      d2[0] = __floats2half2_rn(acc[rr].x, acc[rr].y);
      d2[1] = __floats2half2_rn(acc[rr].z, acc[rr].w);
    }
  }
}

// ---- Stage 1: histogram | gemm tiles [tbase, tbase+tcnt) ----
union HistSmem { int h[NBUCK]; float sW[64 * 128]; };
__global__ __launch_bounds__(256, 4) void hist_gemm_kernel(
    const int* __restrict__ dst, int* __restrict__ gh, int e, int chunk,
    const float* __restrict__ A, const float* __restrict__ W,
    __half* __restrict__ Ch, int n, int tbase) {
  __shared__ HistSmem sm;
  if (blockIdx.x < (unsigned)NBLK) {
    for (int t = threadIdx.x; t < NBUCK; t += 256) sm.h[t] = 0;
    __syncthreads();
    int beg = blockIdx.x * chunk;
    int fin = min(e, beg + chunk);
    for (int i = beg + threadIdx.x; i < fin; i += 256)
      atomicAdd(&sm.h[dst[i] / R], 1);
    __syncthreads();
    for (int t = threadIdx.x; t < NBUCK; t += 256)
      gh[t * NBLK + blockIdx.x] = sm.h[t];
  } else {
    gemm_tile32(tbase + (blockIdx.x - NBLK), A, W, Ch, n, sm.sW);
  }
}

// ---- Stage 2: bscan (offsets gh->ghs) | gemm tiles ----
union BscanSmem { struct { int s[256]; int sBase[NBUCK + 1]; } b; float sW[64 * 128]; };
__global__ __launch_bounds__(256, 4) void bscan_gemm_kernel(
    const int* __restrict__ gh, int* __restrict__ ghs,
    int* __restrict__ rowptr_n,
    const float* __restrict__ A, const float* __restrict__ W,
    __half* __restrict__ Ch, int n, int tbase) {
  __shared__ BscanSmem sm;
  const int tid = threadIdx.x;
  if (blockIdx.x < (unsigned)NBUCK) {
    const int b = blockIdx.x;
    // per-bucket totals (thread t sums bucket-row t; L2-resident)
    int tot = 0;
    if (tid < NBUCK) {
      const int* row = gh + tid * NBLK;
      for (int k = 0; k < NBLK; ++k) tot += row[k];
    }
    sm.b.s[tid] = tot;
    __syncthreads();
    for (int off = 1; off < 256; off <<= 1) {
      int t = (tid >= off) ? sm.b.s[tid - off] : 0;
      __syncthreads();
      sm.b.s[tid] += t;
      __syncthreads();
    }
    if (tid < NBUCK) sm.b.sBase[tid] = sm.b.s[tid] - tot;  // exclusive base
    if (tid == NBUCK - 1) sm.b.sBase[NBUCK] = sm.b.s[tid]; // total == e
    __syncthreads();

    // own-bucket local scan -> global offsets
    int v = (tid < NBLK) ? gh[b * NBLK + tid] : 0;
    sm.b.s[tid] = v;
    __syncthreads();
    for (int off = 1; off < 256; off <<= 1) {
      int t = (tid >= off) ? sm.b.s[tid - off] : 0;
      __syncthreads();
      sm.b.s[tid] += t;
      __syncthreads();
    }
    if (tid < NBLK) ghs[b * NBLK + tid] = sm.b.s[tid] - v + sm.b.sBase[b];
    if (b == 0 && tid == 0) *rowptr_n = sm.b.sBase[NBUCK];
  } else {
    gemm_tile32(tbase + (blockIdx.x - NBUCK), A, W, Ch, n, sm.sW);
  }
}

// ---- Stage 3: scatter | gemm tiles ----
union ScatSmem { int cur[NBUCK]; float sW[64 * 128]; };
__global__ __launch_bounds__(256, 4) void scatter_gemm_kernel(
    const int* __restrict__ src, const int* __restrict__ dst,
    const int* __restrict__ ghs, int* __restrict__ binned, int e, int chunk,
    const float* __restrict__ A, const float* __restrict__ W,
    __half* __restrict__ Ch, int n, int tbase) {
  __shared__ ScatSmem sm;
  if (blockIdx.x < (unsigned)NBLK) {
    for (int t = threadIdx.x; t < NBUCK; t += 256)
      sm.cur[t] = ghs[t * NBLK + blockIdx.x];
    __syncthreads();
    int beg = blockIdx.x * chunk;
    int fin = min(e, beg + chunk);
    for (int i = beg + threadIdx.x; i < fin; i += 256) {
      int d = dst[i];
      int b = d / R;
      int p = atomicAdd(&sm.cur[b], 1);
      binned[p] = ((d - b * R) << 16) | src[i];
    }
  } else {
    gemm_tile32(tbase + (blockIdx.x - NBLK), A, W, Ch, n, sm.sW);
  }
}

// ---- Stage 4: final (deg/rowptr/dinv/csr) | gemm tiles ----
union FinSmem {
  struct { int sdeg[R]; int sscan[256]; int scur[R]; int slab[SLABCAP]; } f;
  float sW[64 * 128];
};
__global__ __launch_bounds__(256, 3) void final_gemm_kernel(
    const int* __restrict__ binned, const int* __restrict__ ghs,
    int* __restrict__ rowptr, int* __restrict__ csr,
    float* __restrict__ dinv, int n, int e,
    const float* __restrict__ A, const float* __restrict__ W,
    __half* __restrict__ Ch, int tbase, int T) {
  __shared__ FinSmem sm;
  const int tid = threadIdx.x;
  if (blockIdx.x < (unsigned)NBUCK) {
    const int b = blockIdx.x;
    const int base = ghs[b * NBLK];
    const int endv = (b < NBUCK - 1) ? ghs[(b + 1) * NBLK] : e;
    const int cnt = endv - base;

    if (tid < R) sm.f.sdeg[tid] = 0;
    __syncthreads();
    for (int k = base + tid; k < endv; k += 256)
      atomicAdd(&sm.f.sdeg[binned[k] >> 16], 1);
    __syncthreads();

    int dv = (tid < R) ? sm.f.sdeg[tid] : 0;
    sm.f.sscan[tid] = dv;
    __syncthreads();
    for (int off = 1; off < 256; off <<= 1) {
      int t = (tid >= off) ? sm.f.sscan[tid - off] : 0;
      __syncthreads();
      sm.f.sscan[tid] += t;
      __syncthreads();
    }
    int excl = sm.f.sscan[tid] - dv;
    int node = b * R + tid;
    if (tid < R && node < n) {
      rowptr[node] = base + excl;
      dinv[node] = 1.0f / sqrtf((float)dv + 1.0f);  // +1 self-loop
      sm.f.scur[tid] = excl;
    }
    __syncthreads();

    const bool fits = (cnt <= SLABCAP);
    for (int k = base + tid; k < endv; k += 256) {
      int rec = binned[k];
      int p = atomicAdd(&sm.f.scur[rec >> 16], 1);
      int s = rec & 0xFFFF;
      if (fits) sm.f.slab[p] = s;
      else csr[base + p] = s;
    }
    __syncthreads();
    if (fits)
      for (int k = tid; k < cnt; k += 256) csr[base + k] = sm.f.slab[k];
  } else {
    int t0 = tbase + (blockIdx.x - NBUCK);
    if (t0 < T) gemm_tile32(t0, A, W, Ch, n, sm.sW);
  }
}

// ---------------------------------------------------------------------------
// GEMM: C[n,M] = A[n,K] @ W[K,M] (+bias). Used for the recon head only.
// ---------------------------------------------------------------------------
template <int K, int M, int KT, int RPT, bool BIAS>
__global__ __launch_bounds__(256, 4) void gemm_kernel(
    const float* __restrict__ A, const float* __restrict__ W,
    const float* __restrict__ bias, float* __restrict__ C, int n) {
  constexpr int CG = M / 4;
  constexpr int RS = 256 / CG;
  constexpr int RPB = RS * RPT;
  __shared__ float sW[KT * M];
  const int cg = threadIdx.x % CG;
  const int rs = threadIdx.x / CG;
  const int row0 = blockIdx.x * RPB + rs * RPT;

  const float* Arow[RPT];
#pragma unroll
  for (int rr = 0; rr < RPT; ++rr) {
    int row = row0 + rr;
    if (row > n - 1) row = n - 1;
    Arow[rr] = A + (size_t)row * K;
  }

  float4 acc[RPT];
#pragma unroll
  for (int rr = 0; rr < RPT; ++rr) acc[rr] = float4{0.f, 0.f, 0.f, 0.f};

  for (int kt = 0; kt < K; kt += KT) {
    if (kt) __syncthreads();
    for (int i = threadIdx.x * 4; i < KT * M; i += 1024)
      *reinterpret_cast<float4*>(&sW[i]) =
          *reinterpret_cast<const float4*>(&W[kt * M + i]);
    __syncthreads();
#pragma unroll 4
    for (int k4 = 0; k4 < KT; k4 += 4) {
      float4 a[RPT];
#pragma unroll
      for (int rr = 0; rr < RPT; ++rr)
        a[rr] = *reinterpret_cast<const float4*>(Arow[rr] + kt + k4);
#pragma unroll
      for (int j = 0; j < 4; ++j) {
        float4 w = *reinterpret_cast<const float4*>(&sW[(k4 + j) * M + cg * 4]);
#pragma unroll
        for (int rr = 0; rr < RPT; ++rr) {
          float av = reinterpret_cast<const float*>(&a[rr])[j];
          acc[rr].x += av * w.x;
          acc[rr].y += av * w.y;
          acc[rr].z += av * w.z;
          acc[rr].w += av * w.w;
        }
      }
    }
  }

  float4 bv = float4{0.f, 0.f, 0.f, 0.f};
  if (BIAS) bv = *reinterpret_cast<const float4*>(&bias[cg * 4]);
#pragma unroll
  for (int rr = 0; rr < RPT; ++rr) {
    int row = row0 + rr;
    if (row < n) {
      float4 o = acc[rr];
      if (BIAS) { o.x += bv.x; o.y += bv.y; o.z += bv.z; o.w += bv.w; }
      *reinterpret_cast<float4*>(&C[(size_t)row * M + cg * 4]) = o;
    }
  }
}

// ---------------------------------------------------------------------------
// SpMM (F=128), one wave per node, U=8 gather pipeline (R9-verified floor).
// SRCSCALE=true : Xs is UNSCALED fp16(xw); apply dinv[src] per edge via a
//                 wave-uniform broadcast load + FMA (spmm1).
// SRCSCALE=false: input already dinv-prescaled (hb) -- byte-exact R6 kernel
//                 (spmm2).
// ---------------------------------------------------------------------------
template <bool SRCSCALE, bool BIAS, bool RELU, bool HALF_OUT>
__global__ __launch_bounds__(256) void spmm128_kernel(
    const __half* __restrict__ Xs, void* __restrict__ Yout,
    const int* __restrict__ rowptr, const int* __restrict__ csr,
    const float* __restrict__ dinv, const float* __restrict__ bias, int n) {
  int wid = (blockIdx.x * blockDim.x + threadIdx.x) >> 6;
  int lane = threadIdx.x & 63;
  if (wid >= n) return;
  int beg = rowptr[wid];
  int end = rowptr[wid + 1];
  constexpr int U = 8;
  float a0[U], a1[U];
#pragma unroll
  for (int uu = 0; uu < U; ++uu) { a0[uu] = 0.f; a1[uu] = 0.f; }

  for (int base = beg; base < end; base += 64) {
    int m = end - base;
    if (m > 64) m = 64;
    int idx = (lane < m) ? csr[base + lane] : 0;
    int j = 0;
    for (; j + U <= m; j += U) {
      const __half2* rows[U];
      float ds[U];
#pragma unroll
      for (int uu = 0; uu < U; ++uu) {
        int i = __shfl(idx, j + uu, 64);
        rows[uu] = reinterpret_cast<const __half2*>(Xs + (size_t)i * 128);
        if (SRCSCALE) ds[uu] = dinv[i];  // wave-uniform broadcast load
      }
      __half2 v[U];
#pragma unroll
      for (int uu = 0; uu < U; ++uu) v[uu] = rows[uu][lane];
#pragma unroll
      for (int uu = 0; uu < U; ++uu) {
        float2 f = __half22float2(v[uu]);
        if (SRCSCALE) {
          a0[uu] += ds[uu] * f.x;
          a1[uu] += ds[uu] * f.y;
        } else {
          a0[uu] += f.x;
          a1[uu] += f.y;
        }
      }
    }
    for (; j < m; ++j) {
      int i = __shfl(idx, j, 64);
      const __half2* row = reinterpret_cast<const __half2*>(Xs + (size_t)i * 128);
      float2 f = __half22float2(row[lane]);
      if (SRCSCALE) {
        float ds = dinv[i];
        a0[0] += ds * f.x;
        a1[0] += ds * f.y;
      } else {
        a0[0] += f.x;
        a1[0] += f.y;
      }
    }
  }

  float t0 = 0.f, t1 = 0.f;
#pragma unroll
  for (int uu = 0; uu < U; ++uu) { t0 += a0[uu]; t1 += a1[uu]; }

  float di = dinv[wid];

  // self-loop: + dinv[wid]*Xs[wid] (SRCSCALE) or + Xs[wid] (prescaled)
  float2 sf = __half22float2(
      reinterpret_cast<const __half2*>(Xs + (size_t)wid * 128)[lane]);
  if (SRCSCALE) {
    t0 += di * sf.x;
    t1 += di * sf.y;
  } else {
    t0 += sf.x;
    t1 += sf.y;
  }

  float r0 = di * t0;
  float r1 = di * t1;
  if (BIAS) { r0 += bias[lane * 2]; r1 += bias[lane * 2 + 1]; }
  if (RELU) { r0 = fmaxf(r0, 0.f); r1 = fmaxf(r1, 0.f); }

  if (HALF_OUT) {
    reinterpret_cast<__half2*>((__half*)Yout + (size_t)wid * 128)[lane] =
        __floats2half2_rn(di * r0, di * r1);
  } else {
    float2 o = {r0, r1};
    reinterpret_cast<float2*>((float*)Yout + (size_t)wid * 128)[lane] = o;
  }
}

// ---------------------------------------------------------------------------
// mlz: fused mu/logvar GEMMs (hagg read ONCE) + z + fp8 z-staging + gender
// logits (commuted, fp32-exact) + label head.
// ---------------------------------------------------------------------------
__global__ __launch_bounds__(256, 4) void mlz_kernel(
    const float* __restrict__ hagg,
    const float* __restrict__ Wmu, const float* __restrict__ bmu,
    const float* __restrict__ Wls, const float* __restrict__ bls,
    const float* __restrict__ eps, const float* __restrict__ dinv,
    const float* __restrict__ Wg, const float* __restrict__ Wlc,
    const float* __restrict__ blc,
    float* __restrict__ out_mu, float* __restrict__ out_lv,
    float* __restrict__ out_z, unsigned int* __restrict__ zh8,
    float2* __restrict__ zgs, float* __restrict__ out_label, int n) {
  constexpr int K = 128, M = 64, KT = 64, RPT = 4;
  constexpr int CG = M / 4;       // 16
  constexpr int RS = 256 / CG;    // 16
  constexpr int RPB = RS * RPT;   // 64
  __shared__ float sWm[KT * M];
  __shared__ float sWl[KT * M];
  const int cg = threadIdx.x % CG;
  const int rs = threadIdx.x / CG;
  const int row0 = blockIdx.x * RPB + rs * RPT;

  const float* Arow[RPT];
#pragma unroll
  for (int rr = 0; rr < RPT; ++rr) {
    int row = row0 + rr;
    if (row > n - 1) row = n - 1;
    Arow[rr] = hagg + (size_t)row * K;
  }

  float4 am[RPT], al[RPT];
#pragma unroll
  for (int rr = 0; rr < RPT; ++rr) {
    am[rr] = float4{0.f, 0.f, 0.f, 0.f};
    al[rr] = float4{0.f, 0.f, 0.f, 0.f};
  }

  for (int kt = 0; kt < K; kt += KT) {
    if (kt) __syncthreads();
    for (int i = threadIdx.x * 4; i < KT * M; i += 1024) {
      *reinterpret_cast<float4*>(&sWm[i]) =
          *reinterpret_cast<const float4*>(&Wmu[kt * M + i]);
      *reinterpret_cast<float4*>(&sWl[i]) =
          *reinterpret_cast<const float4*>(&Wls[kt * M + i]);
    }
    __syncthreads();
#pragma unroll 2
    for (int k4 = 0; k4 < KT; k4 += 4) {
      float4 a[RPT];
#pragma unroll
      for (int rr = 0; rr < RPT; ++rr)
        a[rr] = *reinterpret_cast<const float4*>(Arow[rr] + kt + k4);
#pragma unroll
      for (int j = 0; j < 4; ++j) {
        float4 wm = *reinterpret_cast<const float4*>(&sWm[(k4 + j) * M + cg * 4]);
        float4 wl = *reinterpret_cast<const float4*>(&sWl[(k4 + j) * M + cg * 4]);
#pragma unroll
        for (int rr = 0; rr < RPT; ++rr) {
          float av = reinterpret_cast<const float*>(&a[rr])[j];
          am[rr].x += av * wm.x; am[rr].y += av * wm.y;
          am[rr].z += av * wm.z; am[rr].w += av * wm.w;
          al[rr].x += av * wl.x; al[rr].y += av * wl.y;
          al[rr].z += av * wl.z; al[rr].w += av * wl.w;
        }
      }
    }
  }

  float4 bm = *reinterpret_cast<const float4*>(&bmu[cg * 4]);
  float4 bl = *reinterpret_cast<const float4*>(&bls[cg * 4]);
  float wg0[4], wg1[4], wlcv[4];
#pragma unroll
  for (int cc = 0; cc < 4; ++cc) {
    int c = cg * 4 + cc;
    wg0[cc] = Wg[c * 2 + 0];
    wg1[cc] = Wg[c * 2 + 1];
    wlcv[cc] = Wlc[c];
  }
  float blc0 = blc[0];

#pragma unroll
  for (int rr = 0; rr < RPT; ++rr) {
    int row = row0 + rr;
    if (row < n) {  // uniform across the 16-lane cg-group
      float4 mu4 = {am[rr].x + bm.x, am[rr].y + bm.y,
                    am[rr].z + bm.z, am[rr].w + bm.w};
      float4 lv4 = {al[rr].x + bl.x, al[rr].y + bl.y,
                    al[rr].z + bl.z, al[rr].w + bl.w};
      float4 e4 = *reinterpret_cast<const float4*>(&eps[(size_t)row * 64 + cg * 4]);
      float4 z4 = {e4.x * expf(0.5f * lv4.x) + mu4.x,
                   e4.y * expf(0.5f * lv4.y) + mu4.y,
                   e4.z * expf(0.5f * lv4.z) + mu4.z,
                   e4.w * expf(0.5f * lv4.w) + mu4.w};
      *reinterpret_cast<float4*>(&out_mu[(size_t)row * 64 + cg * 4]) = mu4;
      *reinterpret_cast<float4*>(&out_lv[(size_t)row * 64 + cg * 4]) = lv4;
      *reinterpret_cast<float4*>(&out_z[(size_t)row * 64 + cg * 4]) = z4;
      float di = dinv[row];
      int pw = __builtin_amdgcn_cvt_pk_fp8_f32(di * z4.x, di * z4.y, 0, false);
      pw = __builtin_amdgcn_cvt_pk_fp8_f32(di * z4.z, di * z4.w, pw, true);
      zh8[(size_t)row * 16 + cg] = (unsigned int)pw;
      float pg0 = z4.x * wg0[0] + z4.y * wg0[1] + z4.z * wg0[2] + z4.w * wg0[3];
      float pg1 = z4.x * wg1[0] + z4.y * wg1[1] + z4.z * wg1[2] + z4.w * wg1[3];
      float pl  = z4.x * wlcv[0] + z4.y * wlcv[1] + z4.z * wlcv[2] + z4.w * wlcv[3];
#pragma unroll
      for (int off = 1; off < 16; off <<= 1) {
        pg0 += __shfl_xor(pg0, off, 64);
        pg1 += __shfl_xor(pg1, off, 64);
        pl  += __shfl_xor(pl, off, 64);
      }
      if (cg == 0) {
        zgs[row] = float2{di * pg0, di * pg1};
        out_label[row] = pl + blc0;
      }
    }
  }
}

// ---------------------------------------------------------------------------
// fp8 dword unpack-accumulate: byte b of d is feature 4c+b.
// ---------------------------------------------------------------------------
__device__ __forceinline__ void fp8x4acc(unsigned d, float* a) {
#if defined(__has_builtin) && __has_builtin(__builtin_amdgcn_cvt_pk_f32_fp8)
  typedef float f32x2 __attribute__((ext_vector_type(2)));
  f32x2 lo = __builtin_amdgcn_cvt_pk_f32_fp8((int)d, false);
  f32x2 hi = __builtin_amdgcn_cvt_pk_f32_fp8((int)d, true);
  a[0] += lo.x; a[1] += lo.y; a[2] += hi.x; a[3] += hi.y;
#else
  a[0] += __builtin_amdgcn_cvt_f32_fp8((int)d, 0);
  a[1] += __builtin_amdgcn_cvt_f32_fp8((int)d, 1);
  a[2] += __builtin_amdgcn_cvt_f32_fp8((int)d, 2);
  a[3] += __builtin_amdgcn_cvt_f32_fp8((int)d, 3);
#endif
}

// ---------------------------------------------------------------------------
// spmm_zg (R8-proven): 4 rows per wave-load fp8 dword gather + fused gender
// aggregation (verbatim fp32 path) + gumbel-softmax hard head.
// ---------------------------------------------------------------------------
__global__ __launch_bounds__(256) void spmm_zg_kernel(
    const unsigned char* __restrict__ zh8, const float2* __restrict__ zgs,
    float* __restrict__ zagg, const int* __restrict__ rowptr,
    const int* __restrict__ csr, const float* __restrict__ dinv,
    const float* __restrict__ bg, const float* __restrict__ u,
    float* __restrict__ out_gender, int n) {
  int wid = (blockIdx.x * blockDim.x + threadIdx.x) >> 6;
  int lane = threadIdx.x & 63;
  if (wid >= n) return;
  int beg = rowptr[wid];
  int end = rowptr[wid + 1];
  const int g = lane >> 4;   // row group 0..3
  const int c = lane & 15;   // feature quad: features 4c..4c+3
  const int coff = c * 4;

  float accA[4], accB[4];
#pragma unroll
  for (int f = 0; f < 4; ++f) { accA[f] = 0.f; accB[f] = 0.f; }
  float ga0 = 0.f, ga1 = 0.f;

  for (int base = beg; base < end; base += 64) {
    int m = end - base;
    if (m > 64) m = 64;
    int idx = 0;
    if (lane < m) {
      idx = csr[base + lane];
      float2 gz = zgs[idx];   // per-lane gender-logit accumulation (exact)
      ga0 += gz.x;
      ga1 += gz.y;
    }
    int j = 0;
    for (; j + 8 <= m; j += 8) {
      int i0 = __shfl(idx, j + g, 64);
      int i1 = __shfl(idx, j + 4 + g, 64);
      unsigned d0 = *reinterpret_cast<const unsigned*>(
          zh8 + (size_t)(unsigned)i0 * 64 + coff);
      unsigned d1 = *reinterpret_cast<const unsigned*>(
          zh8 + (size_t)(unsigned)i1 * 64 + coff);
      fp8x4acc(d0, accA);
      fp8x4acc(d1, accB);
    }
    if (j < m) {  // masked trailing step (up to 7 edges)
      int e0 = j + g;
      int e1 = j + 4 + g;
      int i0 = __shfl(idx, min(e0, m - 1), 64);
      int i1 = __shfl(idx, min(e1, m - 1), 64);
      unsigned d0 = *reinterpret_cast<const unsigned*>(
          zh8 + (size_t)(unsigned)i0 * 64 + coff);
      unsigned d1 = *reinterpret_cast<const unsigned*>(
          zh8 + (size_t)(unsigned)i1 * 64 + coff);
      if (e0 >= m) d0 = 0u;   // fp8 0x00 == +0.0
      if (e1 >= m) d1 = 0u;
      fp8x4acc(d0, accA);
      fp8x4acc(d1, accB);
    }
  }

  // combine the 8 partials (zagg order free: recon-only path)
  float t[4];
#pragma unroll
  for (int f = 0; f < 4; ++f) t[f] = accA[f] + accB[f];
#pragma unroll
  for (int f = 0; f < 4; ++f) t[f] += __shfl_xor(t[f], 16, 64);
#pragma unroll
  for (int f = 0; f < 4; ++f) t[f] += __shfl_xor(t[f], 32, 64);

  float di = dinv[wid];
  if (lane < 16) {
    unsigned ds = *reinterpret_cast<const unsigned*>(
        zh8 + (size_t)wid * 64 + coff);
    fp8x4acc(ds, t);  // self-loop
    float4 o = {di * t[0], di * t[1], di * t[2], di * t[3]};
    *reinterpret_cast<float4*>(&zagg[(size_t)wid * 64 + 4 * c]) = o;
  }

  for (int off = 32; off > 0; off >>= 1) {
    ga0 += __shfl_xor(ga0, off, 64);
    ga1 += __shfl_xor(ga1, off, 64);
  }
  if (lane == 0) {
    float2 self = zgs[wid];
    ga0 += self.x;
    ga1 += self.y;
    float lg0 = di * ga0 + bg[0];
    float lg1 = di * ga1 + bg[1];
    float u0 = u[(size_t)wid * 2 + 0];
    float u1 = u[(size_t)wid * 2 + 1];
    float g0 = -logf(-logf(u0 + 1e-20f) + 1e-20f);
    float g1 = -logf(-logf(u1 + 1e-20f) + 1e-20f);
    float a0 = lg0 + g0, a1 = lg1 + g1;
    float mx = fmaxf(a0, a1);
    float e0 = expf(a0 - mx), e1 = expf(a1 - mx);
    float s = e0 + e1;
    float y0 = e0 / s, y1 = e1 / s;
    float h0 = (y1 > y0) ? 0.f : 1.f;  // argmax, first index wins ties
    float h1 = 1.f - h0;
    out_gender[(size_t)wid * 2 + 0] = (h0 - y0) + y0;
    out_gender[(size_t)wid * 2 + 1] = (h1 - y1) + y1;
  }
}

extern "C" void kernel_launch(void* const* d_in, const int* in_sizes, int n_in,
                              void* d_out, int out_size, void* d_ws, size_t ws_size,
                              hipStream_t stream) {
  const float* x   = (const float*)d_in[0];
  const int*   ei  = (const int*)d_in[1];
  const float* eps = (const float*)d_in[2];
  const float* u   = (const float*)d_in[3];
  const float* W1  = (const float*)d_in[4];
  const float* b1  = (const float*)d_in[5];
  const float* Wmu = (const float*)d_in[6];
  const float* bmu = (const float*)d_in[7];
  const float* Wls = (const float*)d_in[8];
  const float* bls = (const float*)d_in[9];
  const float* Wdx = (const float*)d_in[10];
  const float* bdx = (const float*)d_in[11];
  const float* Wg  = (const float*)d_in[12];
  const float* bg  = (const float*)d_in[13];
  const float* Wlc = (const float*)d_in[14];
  const float* blc = (const float*)d_in[15];

  const int n = in_sizes[0] / 128;  // 50000
  const int e = in_sizes[1] / 2;    // 1600000
  const int* esrc = ei;
  const int* edst = ei + e;

  float* out = (float*)d_out;
  float* out_recon  = out;                            // n*128
  float* out_gender = out + (size_t)n * 128;          // n*2
  float* out_label  = out_gender + (size_t)n * 2;     // n
  float* out_mu     = out_label + n;                  // n*64
  float* out_lv     = out_mu + (size_t)n * 64;        // n*64
  float* out_z      = out_lv + (size_t)n * 64;        // n*64

  // Workspace layout, every buffer 256B-aligned.
  char* w = (char*)d_ws;
  size_t off = 0;
  auto alloc = [&](size_t bytes) {
    char* p = w + off;
    off = (off + bytes + 255) & ~(size_t)255;
    return p;
  };
  float* dinv  = (float*)alloc((size_t)n * 4);
  int* rowptr  = (int*)alloc((size_t)(n + 1) * 4);
  int* csr     = (int*)alloc((size_t)e * 4);
  int* gh      = (int*)alloc((size_t)NBUCK * NBLK * 4);
  int* ghs     = (int*)alloc((size_t)NBUCK * NBLK * 4);
  __half* Xs   = (__half*)alloc((size_t)n * 128 * 2);  // later: zh8 (n*64 B)
  __half* hb   = (__half*)alloc((size_t)n * 128 * 2);  // later: zagg (n*64 f32)
  float2* zgs  = (float2*)alloc((size_t)n * 8);
  unsigned char* zh8 = (unsigned char*)Xs;  // alias (Xs dead after spmm1)
  float* zagg  = (float*)hb;                // alias (hb dead after spmm2)
  float* hagg  = out_recon;                 // free until recon GEMM
  int* binned  = (int*)out_lv;              // free until mlz writes out_lv

  const int chunk = (e + NBLK - 1) / NBLK;  // 6400
  const int GBLK = (n + 31) / 32;           // 1563 recon-gemm blocks
  const int T = GBLK;                       // 1563 gemm1 tiles

  // gemm1 tile split across the four CSR launches
  const int TH = 500, TB = 450, TS = 350;
  const int TF = T - TH - TB - TS;          // 263

  // --- CSR build chain, gemm1 tiles spread as filler blocks ---
  hist_gemm_kernel<<<NBLK + TH, 256, 0, stream>>>(
      edst, gh, e, chunk, x, W1, Xs, n, 0);
  bscan_gemm_kernel<<<NBUCK + TB, 256, 0, stream>>>(
      gh, ghs, &rowptr[n], x, W1, Xs, n, TH);
  scatter_gemm_kernel<<<NBLK + TS, 256, 0, stream>>>(
      esrc, edst, ghs, binned, e, chunk, x, W1, Xs, n, TH + TB);
  final_gemm_kernel<<<NBUCK + TF, 256, 0, stream>>>(
      binned, ghs, rowptr, csr, dinv, n, e, x, W1, Xs, TH + TB + TS, T);

  // --- dense/sparse pipeline ---
  // hb = fp16(dinv * relu(A_hat*xw + b1)); Xs unscaled -> SRCSCALE gather
  spmm128_kernel<true, true, true, true>
      <<<(n + 3) / 4, 256, 0, stream>>>(Xs, hb, rowptr, csr, dinv, b1, n);
  // hagg = A_hat * h  (fp32, into out_recon region; hb prescaled -> R6-exact)
  spmm128_kernel<false, false, false, false>
      <<<(n + 3) / 4, 256, 0, stream>>>(hb, hagg, rowptr, csr, dinv, nullptr, n);
  // mu / lv / z / zh8 / zgs / label — fused (overwrites binned via out_lv: dead)
  mlz_kernel<<<(n + 63) / 64, 256, 0, stream>>>(
      hagg, Wmu, bmu, Wls, bls, eps, dinv, Wg, Wlc, blc,
      out_mu, out_lv, out_z, (unsigned int*)zh8, zgs, out_label, n);
  // zagg (fp8 gather) + gender aggregation + gumbel head
  spmm_zg_kernel<<<(n + 3) / 4, 256, 0, stream>>>(
      zh8, (const float2*)zgs, zagg, rowptr, csr, dinv, bg, u, out_gender, n);
  // recon = zagg @ W_dx + b_dx (overwrites hagg — dead)
  gemm_kernel<64, 128, 64, 4, true>
      <<<GBLK, 256, 0, stream>>>(zagg, Wdx, bdx, out_recon, n);
}